// Round 2
// baseline (13229.076 us; speedup 1.0000x reference)
//
#include <hip/hip_runtime.h>
#include <stdint.h>

// Problem constants (setup_inputs: B,L,D,H,A = 128,256,128,256,128)
#define LL   256
#define BB   128
#define DD   128
#define HH   256
#define H2C  512
#define H3C  768
#define ADIM 128
#define NCAT 896          // 768 (W) + 128 (W_action_1) concatenated columns
#define MROWS 32768       // L*B
#define EPSV 1e-5f

typedef __attribute__((ext_vector_type(8))) short short8;   // 8 bf16 (4 VGPRs)
typedef __attribute__((ext_vector_type(4))) float f32x4;

__device__ __forceinline__ unsigned short f2bf(float f) {
    unsigned int u = __float_as_uint(f);
    u = (u + 0x7FFFu + ((u >> 16) & 1u)) >> 16;   // RNE bf16 (finite data only)
    return (unsigned short)u;
}
__device__ __forceinline__ float bf2f(unsigned short h) {
    return __uint_as_float(((unsigned int)h) << 16);
}
__device__ __forceinline__ float hsg(float x) {   // hard_sigmoid
    return fminf(fmaxf(0.2f * x + 0.5f, 0.f), 1.f);
}

// ---------------------------------------------------------------- small init
__global__ void init_flags(int* flags) {
    int i = threadIdx.x;
    if (i < 8) flags[i] = 0;      // done[0..3], anyb[0..3]
}

__global__ void build_bcat(const float* __restrict__ b_, const float* __restrict__ ba1,
                           float* __restrict__ bcat) {
    int i = blockIdx.x * 256 + threadIdx.x;
    if (i < NCAT) bcat[i] = (i < H3C) ? b_[i] : ba1[i - H3C];
}

// dmcur = mask.T ; apcur = 0 ; eos[t][b] = dm0[t][b] * (1 - dm0[t+1][b])
__global__ void init_seq(const float* __restrict__ mask, float* __restrict__ apcur,
                         float* __restrict__ dmcur, float* __restrict__ eosb) {
    int i = blockIdx.x * 256 + threadIdx.x;    // over L*B
    if (i >= MROWS) return;
    int t = i >> 7, b = i & 127;
    float dm  = mask[b * LL + t];
    float nxt = (t < LL - 1) ? mask[b * LL + t + 1] : 0.f;
    dmcur[i] = dm;
    apcur[i] = 0.f;
    eosb[i]  = dm * (1.f - nxt);
}

// ---------------------------------------------------------------- conversions
// generic f32 -> (hi,lo) bf16 split, same layout
__global__ void conv_hilo(const float* __restrict__ in, unsigned short* __restrict__ hi,
                          unsigned short* __restrict__ lo, int n, const int* __restrict__ skip) {
    if (skip && *skip) return;
    int i = blockIdx.x * 256 + threadIdx.x;
    if (i >= n) return;
    float v = in[i];
    unsigned short h = f2bf(v);
    hi[i] = h;
    lo[i] = f2bf(v - bf2f(h));
}

// Wcat = [W | W_action_1] (256 x 896), stored TRANSPOSED [c][k] for MFMA B-frags
__global__ void conv_wcatT(const float* __restrict__ W, const float* __restrict__ Wa1,
                           unsigned short* __restrict__ hi, unsigned short* __restrict__ lo) {
    int i = blockIdx.x * 256 + threadIdx.x;   // over NCAT*HH
    if (i >= NCAT * HH) return;
    int c = i / HH, k = i % HH;
    float v = (c < H3C) ? W[k * H3C + c] : Wa1[k * ADIM + (c - H3C)];
    unsigned short h = f2bf(v);
    hi[i] = h;
    lo[i] = f2bf(v - bf2f(h));
}

// W_emb (128 x 256) transposed -> [c][k], K=128
__global__ void conv_wembT(const float* __restrict__ We,
                           unsigned short* __restrict__ hi, unsigned short* __restrict__ lo) {
    int i = blockIdx.x * 256 + threadIdx.x;   // over HH*DD
    if (i >= HH * DD) return;
    int c = i / DD, k = i % DD;
    float v = We[k * HH + c];
    unsigned short h = f2bf(v);
    hi[i] = h;
    lo[i] = f2bf(v - bf2f(h));
}

// ---------------------------------------------------------------- split-bf16 MFMA GEMM
// C[M,N] = A[M,K] * B[K,N], A given as hi/lo bf16 row-major, B given TRANSPOSED [N][K] hi/lo.
// 3-MFMA split (hi*hi + hi*lo + lo*hi) gives ~f32 accuracy. 128x128 tiles, 4 waves.
__global__ __launch_bounds__(256)
void gemm_bf16split(const unsigned short* __restrict__ Ahi, const unsigned short* __restrict__ Alo,
                    const unsigned short* __restrict__ Bhi, const unsigned short* __restrict__ Blo,
                    float* __restrict__ C, int Mi, int Ni, int Ki,
                    const float* __restrict__ bias, int remap, const int* __restrict__ skip)
{
    if (skip && *skip) return;
    __shared__ __attribute__((aligned(16))) unsigned short sA[2][128 * 32];  // [hi/lo][m][k]
    __shared__ __attribute__((aligned(16))) unsigned short sB[2][128 * 32];  // [hi/lo][n][k]
    const int tid = threadIdx.x, lane = tid & 63, wave = tid >> 6;
    const int bm = blockIdx.y * 128, bn = blockIdx.x * 128;
    const int wm = (wave >> 1) * 64, wn = (wave & 1) * 64;
    f32x4 acc[4][4] = {};
    for (int kk = 0; kk < Ki; kk += 32) {
        __syncthreads();
        #pragma unroll
        for (int j = 0; j < 2; ++j) {
            int cidx = tid + j * 256;                     // 0..511 16B chunks
            int r = cidx >> 2, kc = (cidx & 3) << 3;
            *(uint4*)&sA[0][cidx * 8] = *(const uint4*)&Ahi[(size_t)(bm + r) * Ki + kk + kc];
            *(uint4*)&sA[1][cidx * 8] = *(const uint4*)&Alo[(size_t)(bm + r) * Ki + kk + kc];
            *(uint4*)&sB[0][cidx * 8] = *(const uint4*)&Bhi[(size_t)(bn + r) * Ki + kk + kc];
            *(uint4*)&sB[1][cidx * 8] = *(const uint4*)&Blo[(size_t)(bn + r) * Ki + kk + kc];
        }
        __syncthreads();
        short8 a0[4], a1[4], b0[4], b1[4];
        int k8 = (lane >> 4) << 3;
        #pragma unroll
        for (int i = 0; i < 4; ++i) {
            int rA = wm + i * 16 + (lane & 15);
            a0[i] = *(short8*)&sA[0][rA * 32 + k8];
            a1[i] = *(short8*)&sA[1][rA * 32 + k8];
            int rB = wn + i * 16 + (lane & 15);
            b0[i] = *(short8*)&sB[0][rB * 32 + k8];
            b1[i] = *(short8*)&sB[1][rB * 32 + k8];
        }
        #pragma unroll
        for (int i = 0; i < 4; ++i)
        #pragma unroll
        for (int j = 0; j < 4; ++j) {
            acc[i][j] = __builtin_amdgcn_mfma_f32_16x16x32_bf16(a0[i], b0[j], acc[i][j], 0, 0, 0);
            acc[i][j] = __builtin_amdgcn_mfma_f32_16x16x32_bf16(a0[i], b1[j], acc[i][j], 0, 0, 0);
            acc[i][j] = __builtin_amdgcn_mfma_f32_16x16x32_bf16(a1[i], b0[j], acc[i][j], 0, 0, 0);
        }
    }
    // epilogue: C/D layout col=lane&15, row=(lane>>4)*4+q
    int r4 = (lane >> 4) << 2, cl = lane & 15;
    #pragma unroll
    for (int i = 0; i < 4; ++i)
    #pragma unroll
    for (int j = 0; j < 4; ++j)
    #pragma unroll
    for (int q = 0; q < 4; ++q) {
        int row = bm + wm + i * 16 + r4 + q;
        int col = bn + wn + j * 16 + cl;
        float v = acc[i][j][q];
        if (bias) v += bias[col];
        if (remap) {   // embed: A-rows are (b,l); write to xcur[(t*B + b)]
            int b_ = row >> 8, t_ = row & 255;
            C[(size_t)(t_ * BB + b_) * Ni + col] = v;
        } else {
            C[(size_t)row * Ni + col] = v;
        }
    }
}

// ---------------------------------------------------------------- row LN (in place on raw)
// raw row = 896 floats: [0..767] -> LN(raw+b, gamma0, beta0); [768..895] -> raw + ba1 (via bcat)
__global__ __launch_bounds__(256)
void ln_rows(float* __restrict__ raw, const float* __restrict__ bcat,
             const float* __restrict__ gam, const float* __restrict__ bet,
             const int* __restrict__ skip)
{
    if (skip && *skip) return;
    int wave = threadIdx.x >> 6, lane = threadIdx.x & 63;
    size_t row = (size_t)blockIdx.x * 4 + wave;
    float* base = raw + row * NCAT;
    float v[14];
    #pragma unroll
    for (int j = 0; j < 14; ++j) v[j] = base[lane + j * 64] + bcat[lane + j * 64];
    float s = 0.f;
    #pragma unroll
    for (int j = 0; j < 12; ++j) s += v[j];
    #pragma unroll
    for (int o = 32; o; o >>= 1) s += __shfl_down(s, o);
    s = __shfl(s, 0);
    float mean = s / 768.f;
    float q = 0.f;
    #pragma unroll
    for (int j = 0; j < 12; ++j) { float d = v[j] - mean; q += d * d; }
    #pragma unroll
    for (int o = 32; o; o >>= 1) q += __shfl_down(q, o);
    q = __shfl(q, 0);
    float inv = 1.f / (sqrtf(q / 768.f + EPSV) + EPSV);
    #pragma unroll
    for (int j = 0; j < 12; ++j) {
        int c = lane + j * 64;
        base[c] = gam[c] * ((v[j] - mean) * inv) + bet[c];
    }
    #pragma unroll
    for (int j = 12; j < 14; ++j) base[lane + j * 64] = v[j];
}

// ---------------------------------------------------------------- the sequential scan
// One WG handles 2 batch elements through all 256 timesteps. 640 threads:
//   tid 0..511  : column c of U[:, :512] matvec (phase1) + m2 col (phase3) + combine (phase4)
//   tid 512..639: column of U_action_1 matvec; tid 512/513 run per-batch scalar logic.
__global__ __launch_bounds__(640, 1)
void scan_pass(const float* __restrict__ raw,     // [MROWS][896] s1(LN'd)|xa
               const float* __restrict__ xcur,    // [MROWS][256]
               float* __restrict__ hseq,          // [MROWS][256]
               const float* __restrict__ apcur,   // [L*B]
               const float* __restrict__ dmcur,
               const float* __restrict__ eosb,
               float* __restrict__ aseq,
               float* __restrict__ dmseq,
               const float* __restrict__ U,       // [256][768]
               const float* __restrict__ Ua1,     // [256][128]
               const float* __restrict__ W2,      // [128][2]
               const float* __restrict__ b2g,     // [2]
               const float* __restrict__ gam,     // [2][768] full
               const float* __restrict__ bet,
               int llm, int* __restrict__ anyb, const int* __restrict__ skip)
{
    if (skip && *skip) return;
    __shared__ __attribute__((aligned(16))) float hA[HH], hB[HH], rhA[HH], rhB[HH];
    __shared__ float zB[HH];
    __shared__ float g1[H2C], be1[H2C], g2[HH], be2[HH], w2l[2 * ADIM];
    __shared__ float red[96], scal[20];
    const int tid = threadIdx.x, lane = tid & 63, wave = tid >> 6;
    const int b0 = blockIdx.x * 2, b1i = b0 + 1;

    for (int i = tid; i < H2C; i += 640) { g1[i] = gam[H3C + i]; be1[i] = bet[H3C + i]; }
    for (int i = tid; i < HH; i += 640)  { g2[i] = gam[H3C + H2C + i]; be2[i] = bet[H3C + H2C + i]; }
    for (int i = tid; i < 2 * ADIM; i += 640) w2l[i] = W2[i];
    for (int i = tid; i < HH; i += 640) { hA[i] = 0.f; hB[i] = 0.f; }
    float a_tm1A = 0.f, dm_tm1A = 0.f, a_tm1B = 0.f, dm_tm1B = 0.f; // live on tid 512/513
    int anyLocal = 0;
    __syncthreads();

    for (int t = 0; t < LL; ++t) {
        const size_t rA = ((size_t)t * BB + b0)  * NCAT;
        const size_t rB = ((size_t)t * BB + b1i) * NCAT;
        const size_t xAo = ((size_t)t * BB + b0)  * HH;
        const size_t xBo = ((size_t)t * BB + b1i) * HH;

        float accA = 0.f, accB = 0.f;
        float p_ld0 = 0.f, p_ld1 = 0.f, p_ld2 = 0.f, p_ld3 = 0.f;
        float sc_ap = 0.f, sc_dm = 0.f, sc_sdm = 0.f, sc_sem = 0.f;

        // ---- P1: matvecs (prefetch streamed rows first; latency hides under FMAs)
        if (tid < H2C) {
            p_ld0 = raw[rA + tid];                 // s1 row, col tid (batch A)
            p_ld1 = raw[rB + tid];                 // (batch B)
            if (tid < HH) {
                p_ld2 = raw[rA + H2C + tid];       // tanh-part s1 (A)
                p_ld3 = xcur[xAo + tid];           // x_t (A)
            } else {
                p_ld2 = raw[rB + H2C + (tid - HH)];
                p_ld3 = xcur[xBo + (tid - HH)];
            }
            const float* ucol = U + tid;
            for (int k0 = 0; k0 < HH; k0 += 8) {
                float4 ha0 = *(const float4*)&hA[k0];
                float4 ha1 = *(const float4*)&hA[k0 + 4];
                float4 hb0 = *(const float4*)&hB[k0];
                float4 hb1 = *(const float4*)&hB[k0 + 4];
                #pragma unroll
                for (int j = 0; j < 4; ++j) {
                    float w = ucol[(size_t)(k0 + j) * H3C];
                    accA = fmaf(w, (&ha0.x)[j], accA);
                    accB = fmaf(w, (&hb0.x)[j], accB);
                }
                #pragma unroll
                for (int j = 0; j < 4; ++j) {
                    float w = ucol[(size_t)(k0 + 4 + j) * H3C];
                    accA = fmaf(w, (&ha1.x)[j], accA);
                    accB = fmaf(w, (&hb1.x)[j], accB);
                }
            }
        } else {
            const int ca = tid - H2C;
            p_ld0 = raw[rA + H3C + ca];            // xa (A)
            p_ld1 = raw[rB + H3C + ca];            // xa (B)
            if (tid == H2C) {
                sc_ap = apcur[t * BB + b0]; sc_dm = dmcur[t * BB + b0];
                sc_sdm = t ? dmcur[(t - 1) * BB + b0] : 1.f;
                sc_sem = t ? eosb[(t - 1) * BB + b0] : 0.f;
            } else if (tid == H2C + 1) {
                sc_ap = apcur[t * BB + b1i]; sc_dm = dmcur[t * BB + b1i];
                sc_sdm = t ? dmcur[(t - 1) * BB + b1i] : 1.f;
                sc_sem = t ? eosb[(t - 1) * BB + b1i] : 0.f;
            }
            const float* ucol = Ua1 + ca;
            for (int k0 = 0; k0 < HH; k0 += 8) {
                float4 ha0 = *(const float4*)&hA[k0];
                float4 ha1 = *(const float4*)&hA[k0 + 4];
                float4 hb0 = *(const float4*)&hB[k0];
                float4 hb1 = *(const float4*)&hB[k0 + 4];
                #pragma unroll
                for (int j = 0; j < 4; ++j) {
                    float w = ucol[(size_t)(k0 + j) * ADIM];
                    accA = fmaf(w, (&ha0.x)[j], accA);
                    accB = fmaf(w, (&hb0.x)[j], accB);
                }
                #pragma unroll
                for (int j = 0; j < 4; ++j) {
                    float w = ucol[(size_t)(k0 + 4 + j) * ADIM];
                    accA = fmaf(w, (&ha1.x)[j], accA);
                    accB = fmaf(w, (&hb1.x)[j], accB);
                }
            }
        }

        // wave-level reductions (whole waves take one branch: no divergence inside a wave)
        if (tid < H2C) {
            float sA_ = accA, qA_ = accA * accA, sB_ = accB, qB_ = accB * accB;
            #pragma unroll
            for (int o = 32; o; o >>= 1) {
                sA_ += __shfl_down(sA_, o); qA_ += __shfl_down(qA_, o);
                sB_ += __shfl_down(sB_, o); qB_ += __shfl_down(qB_, o);
            }
            if (lane == 0) { red[wave * 4 + 0] = sA_; red[wave * 4 + 1] = qA_;
                             red[wave * 4 + 2] = sB_; red[wave * 4 + 3] = qB_; }
        } else {
            const int ca = tid - H2C;
            float polA = fmaxf(p_ld0 + accA, 0.f);
            float polB = fmaxf(p_ld1 + accB, 0.f);
            float lA0 = polA * w2l[ca * 2], lA1 = polA * w2l[ca * 2 + 1];
            float lB0 = polB * w2l[ca * 2], lB1 = polB * w2l[ca * 2 + 1];
            #pragma unroll
            for (int o = 32; o; o >>= 1) {
                lA0 += __shfl_down(lA0, o); lA1 += __shfl_down(lA1, o);
                lB0 += __shfl_down(lB0, o); lB1 += __shfl_down(lB1, o);
            }
            if (lane == 0) { int w8 = wave - 8;
                red[32 + w8 * 4 + 0] = lA0; red[32 + w8 * 4 + 1] = lA1;
                red[32 + w8 * 4 + 2] = lB0; red[32 + w8 * 4 + 3] = lB1; }
        }
        __syncthreads();  // B1

        // ---- P2a: per-batch serial logic on tid 512 (A) / 513 (B)
        if (tid == H2C || tid == H2C + 1) {
            int isB = tid - H2C;
            float s = 0.f, q = 0.f;
            #pragma unroll
            for (int w = 0; w < 8; ++w) { s += red[w * 4 + isB * 2]; q += red[w * 4 + isB * 2 + 1]; }
            float mean = s / (float)H2C;
            float var = q / (float)H2C - mean * mean;
            float inv = 1.f / (sqrtf(var + EPSV) + EPSV);
            float l0 = red[32 + isB * 2] + red[36 + isB * 2] + b2g[0];
            float l1 = red[33 + isB * 2] + red[37 + isB * 2] + b2g[1];
            float p0 = fminf(expf(l0), 1000.f);
            float p1 = fminf(expf(l1), 1000.f);
            float act = (p0 <= p1) ? 1.f : 0.f;
            if (sc_ap  > 0.f) act = 1.f;
            if (llm    > 0)   act = 1.f;
            if (sc_sem > 0.f) act = 0.f;
            float a_tm1 = isB ? a_tm1B : a_tm1A;
            float dm_tm1 = isB ? dm_tm1B : dm_tm1A;
            float both   = (1.f - sc_ap) * sc_dm * act * dm_tm1;
            float h_only = dm_tm1 * act * (sc_ap + (1.f - sc_ap) * (1.f - sc_dm));
            float x_only = sc_dm * (1.f - sc_ap) * (1.f - act + act * (1.f - dm_tm1));
            float dmnew  = both + x_only + h_only;
            float a_out  = (sc_sdm > 0.f) ? act : a_tm1;
            int bidx = isB ? b1i : b0;
            aseq[t * BB + bidx]  = a_out;
            dmseq[t * BB + bidx] = dmnew;
            if (isB) { a_tm1B = a_out; dm_tm1B = dmnew; }
            else     { a_tm1A = a_out; dm_tm1A = dmnew; }
            anyLocal |= (both > 0.f) ? 1 : 0;
            int o = isB * 8;
            scal[o + 0] = mean; scal[o + 1] = inv; scal[o + 2] = both;
            scal[o + 3] = h_only; scal[o + 4] = x_only; scal[o + 5] = sc_dm;
        }
        __syncthreads();  // B2

        // ---- P2b: z / r from s2 = LN(m1)
        float zA_r = 0.f, m2acc = 0.f;
        if (tid < HH) {
            float s2A = g1[tid] * ((accA - scal[0]) * scal[1]) + be1[tid];
            float s2B = g1[tid] * ((accB - scal[8]) * scal[9]) + be1[tid];
            zA_r = hsg(p_ld0 + s2A);
            zB[tid] = hsg(p_ld1 + s2B);
        } else if (tid < H2C) {
            int k = tid - HH;
            float s2A = g1[tid] * ((accA - scal[0]) * scal[1]) + be1[tid];
            float s2B = g1[tid] * ((accB - scal[8]) * scal[9]) + be1[tid];
            float rA_ = hsg(p_ld0 + s2A);
            float rB_ = hsg(p_ld1 + s2B);
            rhA[k] = rA_ * hA[k];
            rhB[k] = rB_ * hB[k];
        }
        __syncthreads();  // B3

        // ---- P3: m2 = (r*h) @ U[:, 512:768]
        if (tid < H2C) {
            int col = tid & (HH - 1);
            const float* ucol = U + H2C + col;
            const float* rh = (tid < HH) ? rhA : rhB;
            float acc2 = 0.f;
            for (int k0 = 0; k0 < HH; k0 += 8) {
                float4 r0 = *(const float4*)&rh[k0];
                float4 r1 = *(const float4*)&rh[k0 + 4];
                #pragma unroll
                for (int j = 0; j < 4; ++j) acc2 = fmaf(ucol[(size_t)(k0 + j) * H3C], (&r0.x)[j], acc2);
                #pragma unroll
                for (int j = 0; j < 4; ++j) acc2 = fmaf(ucol[(size_t)(k0 + 4 + j) * H3C], (&r1.x)[j], acc2);
            }
            m2acc = acc2;
            float s_ = acc2, q_ = acc2 * acc2;
            #pragma unroll
            for (int o = 32; o; o >>= 1) { s_ += __shfl_down(s_, o); q_ += __shfl_down(q_, o); }
            if (lane == 0) { red[48 + wave * 2] = s_; red[48 + wave * 2 + 1] = q_; }
        }
        __syncthreads();  // B4

        if (tid == H2C || tid == H2C + 1) {
            int isB = tid - H2C;
            float s = 0.f, q = 0.f;
            #pragma unroll
            for (int w = 0; w < 4; ++w) { s += red[48 + (isB * 4 + w) * 2]; q += red[48 + (isB * 4 + w) * 2 + 1]; }
            float mean = s / (float)HH;
            float var = q / (float)HH - mean * mean;
            float inv = 1.f / (sqrtf(var + EPSV) + EPSV);
            scal[16 + isB * 2] = mean; scal[17 + isB * 2] = inv;
        }
        __syncthreads();  // B5

        // ---- P4: combine, update h
        if (tid < H2C) {
            int col = tid & (HH - 1);
            int isB = (tid >= HH) ? 1 : 0;
            float mean2 = scal[16 + isB * 2], inv2 = scal[17 + isB * 2];
            float ln2 = g2[col] * ((m2acc - mean2) * inv2) + be2[col];
            float tc = tanhf(p_ld2 + ln2);
            float z = isB ? zB[col] : zA_r;
            float* hArr = isB ? hB : hA;
            float hprev = hArr[col];
            float hcand = z * hprev + (1.f - z) * tc;
            int o = isB * 8;
            float hn = scal[o + 2] * hcand + scal[o + 3] * hprev + scal[o + 4] * p_ld3;
            hn = (scal[o + 5] > 0.f) ? hn : hprev;
            hseq[(isB ? xBo : xAo) + col] = hn;
            hArr[col] = hn;
        }
        __syncthreads();  // B6
    }
    if ((tid == H2C || tid == H2C + 1) && anyLocal) atomicOr(anyb, 1);
}

// ---------------------------------------------------------------- commit (vstep glue)
__global__ void commit_pass(float* __restrict__ xcur, const float* __restrict__ hseq,
                            float* __restrict__ apcur, const float* __restrict__ aseq,
                            float* __restrict__ dmcur, const float* __restrict__ dmseq,
                            const int* __restrict__ donep, int* __restrict__ donep1,
                            const int* __restrict__ anyb)
{
    size_t i = (size_t)blockIdx.x * 256 + threadIdx.x;
    int done = *donep;
    if (blockIdx.x == 0 && threadIdx.x == 0)
        *donep1 = done | ((*anyb == 0) ? 1 : 0);
    if (done) return;
    if (i < (size_t)MROWS * HH) xcur[i] = hseq[i];
    if (i < MROWS) {
        int t = (int)(i >> 7);
        apcur[i] = (t < LL - 1) ? aseq[i + BB] : 0.f;
        dmcur[i] = dmseq[i];
    }
}

__global__ void write_out(const float* __restrict__ hseq, float* __restrict__ outp) {
    int i = blockIdx.x * 256 + threadIdx.x;   // 32768 = B*H
    if (i >= BB * HH) return;
    int b = i >> 8, h = i & 255;
    outp[i] = hseq[((size_t)(LL - 1) * BB + b) * HH + h];
}

// ---------------------------------------------------------------- launcher
static inline size_t alignUp(size_t v) { return (v + 255) & ~(size_t)255; }

extern "C" void kernel_launch(void* const* d_in, const int* in_sizes, int n_in,
                              void* d_out, int out_size, void* d_ws, size_t ws_size,
                              hipStream_t stream) {
    (void)in_sizes; (void)n_in; (void)out_size; (void)ws_size;
    const float* x     = (const float*)d_in[0];
    const float* mask  = (const float*)d_in[1];
    const float* W_emb = (const float*)d_in[3];
    const float* b_emb = (const float*)d_in[4];
    const float* W     = (const float*)d_in[5];
    const float* U     = (const float*)d_in[6];
    const float* bvec  = (const float*)d_in[7];
    const float* Wa1   = (const float*)d_in[8];
    const float* Ua1   = (const float*)d_in[9];
    const float* ba1   = (const float*)d_in[10];
    const float* W2    = (const float*)d_in[11];
    const float* b2    = (const float*)d_in[12];
    const float* gam   = (const float*)d_in[13];
    const float* bet   = (const float*)d_in[14];
    float* outp = (float*)d_out;

    char* ws = (char*)d_ws;
    size_t off = 0;
    auto take = [&](size_t bytes) { char* p = ws + off; off = alignUp(off + bytes); return p; };
    float* raw  = (float*)take((size_t)MROWS * NCAT * 4);     // 117.4 MB
    float* xcur = (float*)take((size_t)MROWS * HH * 4);       // 33.5 MB
    float* hseq = (float*)take((size_t)MROWS * HH * 4);       // 33.5 MB
    unsigned short* Ahi = (unsigned short*)take((size_t)MROWS * HH * 2);   // 16.8 MB (also reused for x-conv)
    unsigned short* Alo = (unsigned short*)take((size_t)MROWS * HH * 2);
    unsigned short* WcT_hi = (unsigned short*)take((size_t)NCAT * HH * 2);
    unsigned short* WcT_lo = (unsigned short*)take((size_t)NCAT * HH * 2);
    unsigned short* WeT_hi = (unsigned short*)take((size_t)HH * DD * 2);
    unsigned short* WeT_lo = (unsigned short*)take((size_t)HH * DD * 2);
    float* apcur = (float*)take((size_t)MROWS * 4);
    float* dmcur = (float*)take((size_t)MROWS * 4);
    float* eosb  = (float*)take((size_t)MROWS * 4);
    float* aseq  = (float*)take((size_t)MROWS * 4);
    float* dmseq = (float*)take((size_t)MROWS * 4);
    float* bcat  = (float*)take((size_t)NCAT * 4);
    int* flags   = (int*)take(64);
    int* done = flags;        // done[0..3]
    int* anyb = flags + 4;    // anyb[0..3]

    init_flags<<<1, 64, 0, stream>>>(flags);
    build_bcat<<<4, 256, 0, stream>>>(bvec, ba1, bcat);
    conv_wcatT<<<(NCAT * HH + 255) / 256, 256, 0, stream>>>(W, Wa1, WcT_hi, WcT_lo);
    conv_wembT<<<(HH * DD + 255) / 256, 256, 0, stream>>>(W_emb, WeT_hi, WeT_lo);
    init_seq<<<MROWS / 256, 256, 0, stream>>>(mask, apcur, dmcur, eosb);

    // embed: xcur[(t,b)] = x[(b,l)] @ W_emb + b_emb   (x converted into Ahi/Alo, K=128)
    conv_hilo<<<(MROWS * DD) / 256, 256, 0, stream>>>(x, Ahi, Alo, MROWS * DD, nullptr);
    gemm_bf16split<<<dim3(HH / 128, MROWS / 128), 256, 0, stream>>>(
        Ahi, Alo, WeT_hi, WeT_lo, xcur, MROWS, HH, DD, b_emb, 1, nullptr);

    for (int p = 0; p < 4; ++p) {
        const int* skip = (p == 1 || p == 2) ? &done[p] : nullptr;
        conv_hilo<<<(MROWS * HH) / 256, 256, 0, stream>>>(xcur, Ahi, Alo, MROWS * HH, skip);
        gemm_bf16split<<<dim3(NCAT / 128, MROWS / 128), 256, 0, stream>>>(
            Ahi, Alo, WcT_hi, WcT_lo, raw, MROWS, NCAT, HH, nullptr, 0, skip);
        ln_rows<<<MROWS / 4, 256, 0, stream>>>(raw, bcat, gam, bet, skip);
        scan_pass<<<BB / 2, 640, 0, stream>>>(raw, xcur, hseq, apcur, dmcur, eosb,
                                              aseq, dmseq, U, Ua1, W2, b2, gam, bet,
                                              (p == 3) ? 1 : 0, &anyb[p], skip);
        if (p < 3)
            commit_pass<<<(MROWS * HH) / 256, 256, 0, stream>>>(
                xcur, hseq, apcur, aseq, dmcur, dmseq, &done[p], &done[p + 1], &anyb[p]);
    }
    write_out<<<(BB * HH) / 256, 256, 0, stream>>>(hseq, outp);
}